// Round 3
// baseline (40.595 us; speedup 1.0000x reference)
//
#include <hip/hip_runtime.h>

#define DIM 120
#define NB 32            // batch rows per block
#define NBP 36           // padded LDS stride in dwords (multiple of 4 -> b128-aligned)
#define BLOCK 256        // one thread per output row

// ---- Fused preprocess: CSR row pointers + packed {i1,i2,palette} entries ----
__global__ void pre_kernel(const int* __restrict__ out_idx, int K, int H,
                           int* __restrict__ row_start,
                           const int* __restrict__ i1, const int* __restrict__ i2,
                           const int* __restrict__ cb, const float* __restrict__ pal,
                           uint2* __restrict__ ent) {
    int t = blockIdx.x * blockDim.x + threadIdx.x;
    if (t <= H) {
        int lo = 0, hi = K;
        while (lo < hi) {
            int mid = (lo + hi) >> 1;
            if (out_idx[mid] < t) lo = mid + 1; else hi = mid;
        }
        row_start[t] = lo;
    }
    if (t < K) {
        uint2 e;
        e.x = (unsigned)i1[t] | ((unsigned)i2[t] << 16);
        e.y = __float_as_uint(pal[cb[t]]);
        ent[t] = e;
    }
}

// ---- Main: thread = one output row o x NB batch rows.
// LDS tiles transposed to [d][b] (padded stride NBP) so each entry's batch
// sweep is NB/4 ds_read_b128 per operand instead of NB ds_read_b32.
__global__ __launch_bounds__(BLOCK) void tp_kernel(
    const float* __restrict__ in1, const float* __restrict__ in2,
    const uint2* __restrict__ ent, const int* __restrict__ row_start,
    float* __restrict__ out, int H) {
    __shared__ float s1t[DIM * NBP];
    __shared__ float s2t[DIM * NBP];

    const int b0 = blockIdx.y * NB;
    {
        const float4* __restrict__ p1 = (const float4*)(in1 + (size_t)b0 * DIM);
        const float4* __restrict__ p2 = (const float4*)(in2 + (size_t)b0 * DIM);
        for (int t = threadIdx.x; t < NB * DIM / 4; t += BLOCK) {
            const int b  = t / (DIM / 4);
            const int d  = (t % (DIM / 4)) * 4;
            const float4 x = p1[t];
            const float4 y = p2[t];
            s1t[(d + 0) * NBP + b] = x.x; s1t[(d + 1) * NBP + b] = x.y;
            s1t[(d + 2) * NBP + b] = x.z; s1t[(d + 3) * NBP + b] = x.w;
            s2t[(d + 0) * NBP + b] = y.x; s2t[(d + 1) * NBP + b] = y.y;
            s2t[(d + 2) * NBP + b] = y.z; s2t[(d + 3) * NBP + b] = y.w;
        }
    }
    __syncthreads();

    const int o = blockIdx.x * BLOCK + threadIdx.x;
    if (o >= H) return;
    const int k0 = row_start[o];
    const int k1 = row_start[o + 1];

    float acc[NB];
#pragma unroll
    for (int b = 0; b < NB; ++b) acc[b] = 0.0f;

    for (int k = k0; k < k1; ++k) {
        const uint2 e = ent[k];
        const float4* __restrict__ pa = (const float4*)(s1t + (e.x & 0xffffu) * NBP);
        const float4* __restrict__ pc = (const float4*)(s2t + (e.x >> 16) * NBP);
        const float v = __uint_as_float(e.y);
#pragma unroll
        for (int j = 0; j < NB / 4; ++j) {
            const float4 x = pa[j];
            const float4 y = pc[j];
            acc[4 * j + 0] = fmaf(v * x.x, y.x, acc[4 * j + 0]);
            acc[4 * j + 1] = fmaf(v * x.y, y.y, acc[4 * j + 1]);
            acc[4 * j + 2] = fmaf(v * x.z, y.z, acc[4 * j + 2]);
            acc[4 * j + 3] = fmaf(v * x.w, y.w, acc[4 * j + 3]);
        }
    }

#pragma unroll
    for (int b = 0; b < NB; ++b)
        out[(size_t)(b0 + b) * H + o] = acc[b];
}

extern "C" void kernel_launch(void* const* d_in, const int* in_sizes, int n_in,
                              void* d_out, int out_size, void* d_ws, size_t ws_size,
                              hipStream_t stream) {
    const float* in1 = (const float*)d_in[0];
    const float* in2 = (const float*)d_in[1];
    const float* pal = (const float*)d_in[2];
    const int*   i1  = (const int*)d_in[3];
    const int*   i2  = (const int*)d_in[4];
    const int*   oi  = (const int*)d_in[5];
    const int*   cb  = (const int*)d_in[6];

    const int K = in_sizes[3];
    const int B = in_sizes[0] / DIM;   // 2048
    const int H = out_size / B;        // 14400

    uint2* ent = (uint2*)d_ws;
    int* row_start = (int*)((char*)d_ws + (size_t)K * sizeof(uint2));

    {
        const int n = (K > H + 1) ? K : (H + 1);
        pre_kernel<<<(n + 255) / 256, 256, 0, stream>>>(oi, K, H, row_start,
                                                        i1, i2, cb, pal, ent);
    }

    dim3 grid((H + BLOCK - 1) / BLOCK, B / NB);
    tp_kernel<<<grid, BLOCK, 0, stream>>>(in1, in2, ent, row_start,
                                          (float*)d_out, H);
}

// Round 4
// 34.438 us; speedup vs baseline: 1.1788x; 1.1788x over previous
//
#include <hip/hip_runtime.h>

#define DIM 120
#define NB 16            // batch rows per block
#define NBP 20           // padded LDS stride in dwords (multiple of 4 -> b128-aligned)
#define BLOCK 256        // one thread per output row
#define NG (NB / 4)      // float4 groups along b

// ---- Fused preprocess: CSR row pointers + packed {i1,i2,palette} entries ----
__global__ void pre_kernel(const int* __restrict__ out_idx, int K, int H,
                           int* __restrict__ row_start,
                           const int* __restrict__ i1, const int* __restrict__ i2,
                           const int* __restrict__ cb, const float* __restrict__ pal,
                           uint2* __restrict__ ent) {
    int t = blockIdx.x * blockDim.x + threadIdx.x;
    if (t <= H) {
        int lo = 0, hi = K;
        while (lo < hi) {
            int mid = (lo + hi) >> 1;
            if (out_idx[mid] < t) lo = mid + 1; else hi = mid;
        }
        row_start[t] = lo;
    }
    if (t < K) {
        uint2 e;
        e.x = (unsigned)i1[t] | ((unsigned)i2[t] << 16);
        e.y = __float_as_uint(pal[cb[t]]);
        ent[t] = e;
    }
}

// ---- Main: thread = one output row o x NB batch rows.
// LDS transposed [d][b] (stride NBP): per entry, NG ds_read_b128 per operand.
// Staging: cell=(d,g): 4 strided global scalar loads + one ds_write_b128;
// consecutive-d lanes spread across all 8 b128 start-bank groups.
__global__ __launch_bounds__(BLOCK, 8) void tp_kernel(
    const float* __restrict__ in1, const float* __restrict__ in2,
    const uint2* __restrict__ ent, const int* __restrict__ row_start,
    float* __restrict__ out, int H) {
    __shared__ __align__(16) float s1t[DIM * NBP];
    __shared__ __align__(16) float s2t[DIM * NBP];

    const int b0 = blockIdx.y * NB;
    for (int t = threadIdx.x; t < 2 * DIM * NG; t += BLOCK) {
        const int arr = (t >= DIM * NG);
        const int c = arr ? t - DIM * NG : t;
        const int d = c % DIM;
        const int g = c / DIM;
        const float* __restrict__ src = arr ? in2 : in1;
        const size_t base = (size_t)(b0 + 4 * g) * DIM + d;
        float4 v;
        v.x = src[base + 0 * DIM];
        v.y = src[base + 1 * DIM];
        v.z = src[base + 2 * DIM];
        v.w = src[base + 3 * DIM];
        float* dst = arr ? s2t : s1t;
        *(float4*)(dst + d * NBP + 4 * g) = v;
    }
    __syncthreads();

    const int o = blockIdx.x * BLOCK + threadIdx.x;
    if (o >= H) return;
    const int k0 = row_start[o];
    const int k1 = row_start[o + 1];

    float acc[NB];
#pragma unroll
    for (int b = 0; b < NB; ++b) acc[b] = 0.0f;

    for (int k = k0; k < k1; ++k) {
        const uint2 e = ent[k];
        const float4* __restrict__ pa = (const float4*)(s1t + (e.x & 0xffffu) * NBP);
        const float4* __restrict__ pc = (const float4*)(s2t + (e.x >> 16) * NBP);
        const float v = __uint_as_float(e.y);
#pragma unroll
        for (int j = 0; j < NG; ++j) {
            const float4 x = pa[j];
            const float4 y = pc[j];
            acc[4 * j + 0] = fmaf(v * x.x, y.x, acc[4 * j + 0]);
            acc[4 * j + 1] = fmaf(v * x.y, y.y, acc[4 * j + 1]);
            acc[4 * j + 2] = fmaf(v * x.z, y.z, acc[4 * j + 2]);
            acc[4 * j + 3] = fmaf(v * x.w, y.w, acc[4 * j + 3]);
        }
    }

#pragma unroll
    for (int b = 0; b < NB; ++b)
        out[(size_t)(b0 + b) * H + o] = acc[b];
}

extern "C" void kernel_launch(void* const* d_in, const int* in_sizes, int n_in,
                              void* d_out, int out_size, void* d_ws, size_t ws_size,
                              hipStream_t stream) {
    const float* in1 = (const float*)d_in[0];
    const float* in2 = (const float*)d_in[1];
    const float* pal = (const float*)d_in[2];
    const int*   i1  = (const int*)d_in[3];
    const int*   i2  = (const int*)d_in[4];
    const int*   oi  = (const int*)d_in[5];
    const int*   cb  = (const int*)d_in[6];

    const int K = in_sizes[3];
    const int B = in_sizes[0] / DIM;   // 2048
    const int H = out_size / B;        // 14400

    uint2* ent = (uint2*)d_ws;
    int* row_start = (int*)((char*)d_ws + (size_t)K * sizeof(uint2));

    {
        const int n = (K > H + 1) ? K : (H + 1);
        pre_kernel<<<(n + 255) / 256, 256, 0, stream>>>(oi, K, H, row_start,
                                                        i1, i2, cb, pal, ent);
    }

    dim3 grid((H + BLOCK - 1) / BLOCK, B / NB);
    tp_kernel<<<grid, BLOCK, 0, stream>>>(in1, in2, ent, row_start,
                                          (float*)d_out, H);
}